// Round 6
// baseline (717.208 us; speedup 1.0000x reference)
//
#include <hip/hip_runtime.h>

typedef unsigned long long u64;

#define THR 0.5f

// Convert one cxcywh box to ltrb + area, with FP contraction OFF so every op
// matches numpy's rn-per-op semantics bit-exactly (needed for the NMS >= 0.5
// predicate; a fused cx - 0.5*w -> fma differs in the last ulp).
__device__ __forceinline__ void conv_box(const float4 b, float& l, float& t,
                                         float& r, float& bo, float& a) {
  #pragma clang fp contract(off)
  float hw = 0.5f * b.z;
  float hh = 0.5f * b.w;
  l = b.x - hw;
  t = b.y - hh;
  r = b.x + hw;
  bo = b.y + hh;
  a = (r - l) * (bo - t);
}

// Fused rank+scatter (atomic-free): thread i counts its stable descending
// rank over ALL scores (float4-vectorized, scores L1/L2-resident), then
// scatters its converted box to the sorted SoA position.
__global__ void k_rankscatter(const float4* __restrict__ boxes,
                              const float* __restrict__ scores,
                              float* __restrict__ sl, float* __restrict__ st,
                              float* __restrict__ sr, float* __restrict__ sb,
                              float* __restrict__ sa, int* __restrict__ sidx, int n) {
  int i = blockIdx.x * blockDim.x + threadIdx.x;
  if (i >= n) return;
  float si = scores[i];
  const float4* s4 = (const float4*)scores;
  int n4 = n >> 2;
  int c = 0;
  for (int j4 = 0; j4 < n4; ++j4) {
    float4 v = s4[j4];
    int j = j4 << 2;
    c += (v.x > si || (v.x == si && j + 0 < i)) ? 1 : 0;
    c += (v.y > si || (v.y == si && j + 1 < i)) ? 1 : 0;
    c += (v.z > si || (v.z == si && j + 2 < i)) ? 1 : 0;
    c += (v.w > si || (v.w == si && j + 3 < i)) ? 1 : 0;
  }
  for (int j = n4 << 2; j < n; ++j) {
    float sj = scores[j];
    c += (sj > si || (sj == si && j < i)) ? 1 : 0;
  }
  float l, t, r, b, a;
  conv_box(boxes[i], l, t, r, b, a);
  sl[c] = l; st[c] = t; sr[c] = r; sb[c] = b; sa[c] = a; sidx[c] = i;
}

// mask[k][w] bit b (j = w*64+b) set iff j>k, j<n, iou_nms(k,j) >= 0.5.
// Also emits diag (diagonal 64x64 block) and band (superdiagonal word
// mask[k][(k>>6)+1]) for the scan. Reference does NOT clamp the intersection
// on the NMS path — replicate exactly (contraction off, IEEE f32 div).
__global__ void k_mask(const float* __restrict__ sl, const float* __restrict__ st,
                       const float* __restrict__ sr, const float* __restrict__ sb,
                       const float* __restrict__ sa,
                       u64* __restrict__ mask, u64* __restrict__ diag,
                       u64* __restrict__ band, int n, int wstride) {
  #pragma clang fp contract(off)
  int k = blockIdx.x * blockDim.x + threadIdx.x;
  if (k >= n) return;
  int w = blockIdx.y;
  int jbase = w << 6;
  u64 word = 0;
  if (jbase + 63 > k) {
    float l = sl[k], t = st[k], r = sr[k], b = sb[k], a = sa[k];
    int jend = min(jbase + 64, n);
    for (int j = max(jbase, k + 1); j < jend; ++j) {
      float lmax = fmaxf(l, sl[j]);
      float tmax = fmaxf(t, st[j]);
      float rmin = fminf(r, sr[j]);
      float bmin = fminf(b, sb[j]);
      float wd = rmin - lmax;
      float hd = bmin - tmax;
      float inter = wd * hd;               // no clamp (matches reference NMS path)
      float denom = (a + sa[j]) - inter;
      float q = inter / denom;             // IEEE f32 div
      if (q >= THR) word |= 1ull << (j - jbase);
    }
  }
  mask[(size_t)k * wstride + w] = word;
  int kg = k >> 6;
  if (kg == w) diag[k] = word;
  if (w == kg + 1) band[k] = word;
}

// Canonical GCN wave64 OR-reduce: DPP row_shr 1/2/4/8 + bcast15/31 (VALU
// latency ~4-8cy/step) instead of 6 dependent u64 shfl_xor (~120cy bpermutes).
__device__ __forceinline__ u64 wave_or_u64(u64 v) {
  unsigned lo = (unsigned)v, hi = (unsigned)(v >> 32);
#define DPP_OR(x, ctrl, rmask) \
  x |= (unsigned)__builtin_amdgcn_update_dpp(0, (int)(x), ctrl, rmask, 0xF, true)
  DPP_OR(lo, 0x111, 0xF); DPP_OR(hi, 0x111, 0xF);   // row_shr:1
  DPP_OR(lo, 0x112, 0xF); DPP_OR(hi, 0x112, 0xF);   // row_shr:2
  DPP_OR(lo, 0x114, 0xF); DPP_OR(hi, 0x114, 0xF);   // row_shr:4
  DPP_OR(lo, 0x118, 0xF); DPP_OR(hi, 0x118, 0xF);   // row_shr:8
  DPP_OR(lo, 0x142, 0xA); DPP_OR(hi, 0x142, 0xA);   // row_bcast:15 rows 1,3
  DPP_OR(lo, 0x143, 0xC); DPP_OR(hi, 0x143, 0xC);   // row_bcast:31 rows 2,3
#undef DPP_OR
  unsigned flo = (unsigned)__builtin_amdgcn_readlane((int)lo, 63);
  unsigned fhi = (unsigned)__builtin_amdgcn_readlane((int)hi, 63);
  return ((u64)fhi << 32) | flo;
}

// ---------------------------------------------------------------------------
// Greedy serial NMS scan — 256 threads.
//  wave 0: serial chain with the diag block REGISTER-double-buffered
//    (ulonglong2 LDS loads; chunk c+1 issued before compute c; chunk 0 of the
//    next group pre-read BEFORE the barrier). Round-5 bug: VGPR cap 32 forced
//    per-chunk LDS waits (~1200cy/group).
//  band word for g+1 via DPP wave-OR (register, no global/LDS latency).
//  keep bits parked in LDS kwords[]; scattered once after the loop.
//  waves 1-3: lazy fold of group g-1's kept rows into rem[w], w>g, concurrent
//    with the chain; 16-deep independent coalesced loads.
// ---------------------------------------------------------------------------
__device__ __forceinline__ void scan_body7(
    const u64* __restrict__ mask, const u64* __restrict__ diag,
    const u64* __restrict__ band, const int* __restrict__ sidx,
    float* __restrict__ keep, int n, int wstride,
    u64* rem, u64* dsh, u64* bsh, u64* kwords, int (*kept)[64], int* nk_sh) {
  int t = threadIdx.x, wv = t >> 6, lane = t & 63;
  int ng = (n + 63) >> 6;
  rem[t] = 0;
  if (t < 2) nk_sh[t] = 0;
  u64 bnd = 0;
  u64 x0 = 0, x1 = 0, x2 = 0, x3 = 0, x4 = 0, x5 = 0, x6 = 0, x7 = 0;
  const ulonglong2* d2 = (const ulonglong2*)dsh;
  if (wv == 0) {
    dsh[lane] = diag[lane];
    bsh[lane] = band[lane];
    ulonglong2 p0 = d2[0], p1 = d2[1], p2 = d2[2], p3 = d2[3];
    x0 = p0.x; x1 = p0.y; x2 = p1.x; x3 = p1.y;
    x4 = p2.x; x5 = p2.y; x6 = p3.x; x7 = p3.y;
  }
  __syncthreads();
  for (int g = 0; g < ng; ++g) {
    int base = g << 6;
    if (wv == 0) {
      // prefetch next group's diag/band (global; hides under the chain)
      int nxt = base + 64 + lane;
      u64 dnext = (g + 1 < ng) ? diag[nxt] : 0;
      u64 bnext = (g + 1 < ng) ? band[nxt] : 0;
      u64 bshv = bsh[lane];                 // parallel LDS read, off-chain
      u64 s = rem[g] | bnd;                 // bnd = group g-1's word-g bits
      int valid = n - base;
      if (valid < 64) s |= (~0ull) << valid;  // nonexistent boxes = suppressed
      u64 kw = 0;
      u64 y0, y1, y2, y3, y4, y5, y6, y7;
#define LDC(a0,a1,a2,a3,a4,a5,a6,a7, c) { \
      ulonglong2 q0 = d2[4*(c)], q1 = d2[4*(c)+1], q2 = d2[4*(c)+2], q3 = d2[4*(c)+3]; \
      a0 = q0.x; a1 = q0.y; a2 = q1.x; a3 = q1.y; a4 = q2.x; a5 = q2.y; a6 = q3.x; a7 = q3.y; }
#define STEP(BB, EQ) if (!((s >> (BB)) & 1ull)) { kw |= 1ull << (BB); s |= EQ; }
#define CHUNK(b0v, a0,a1,a2,a3,a4,a5,a6,a7) \
      if ((unsigned)((s >> (b0v)) & 0xFFull) != 0xFFu) { \
        STEP(b0v+0, a0) STEP(b0v+1, a1) STEP(b0v+2, a2) STEP(b0v+3, a3) \
        STEP(b0v+4, a4) STEP(b0v+5, a5) STEP(b0v+6, a6) STEP(b0v+7, a7) }
      LDC(y0,y1,y2,y3,y4,y5,y6,y7, 1); CHUNK(0,  x0,x1,x2,x3,x4,x5,x6,x7);
      LDC(x0,x1,x2,x3,x4,x5,x6,x7, 2); CHUNK(8,  y0,y1,y2,y3,y4,y5,y6,y7);
      LDC(y0,y1,y2,y3,y4,y5,y6,y7, 3); CHUNK(16, x0,x1,x2,x3,x4,x5,x6,x7);
      LDC(x0,x1,x2,x3,x4,x5,x6,x7, 4); CHUNK(24, y0,y1,y2,y3,y4,y5,y6,y7);
      LDC(y0,y1,y2,y3,y4,y5,y6,y7, 5); CHUNK(32, x0,x1,x2,x3,x4,x5,x6,x7);
      LDC(x0,x1,x2,x3,x4,x5,x6,x7, 6); CHUNK(40, y0,y1,y2,y3,y4,y5,y6,y7);
      LDC(y0,y1,y2,y3,y4,y5,y6,y7, 7); CHUNK(48, x0,x1,x2,x3,x4,x5,x6,x7);
                                       CHUNK(56, y0,y1,y2,y3,y4,y5,y6,y7);
#undef CHUNK
#undef STEP
#undef LDC
      if (lane == 0) kwords[g] = kw;
      // compact kept bits -> double-buffered LDS list, pad to x16 with 0
      int nk = __popcll(kw);
      if ((kw >> lane) & 1ull) {
        int pos = __popcll(kw & ((1ull << lane) - 1ull));
        kept[g & 1][pos] = lane;
      }
      int npad = (nk + 15) & ~15;
      if (lane >= nk && lane < npad) kept[g & 1][lane] = 0;
      if (lane == 0) nk_sh[g & 1] = nk;
      // band word for group g+1: DPP wave-OR of kept lanes' superdiag words
      u64 bv = ((kw >> lane) & 1ull) ? bshv : 0ull;
      bnd = wave_or_u64(bv);
      dsh[lane] = dnext;     // after all chain reads (wave-ordered LDS)
      bsh[lane] = bnext;
      // pre-read chunk 0 of the NEXT group before the barrier
      ulonglong2 p0 = d2[0], p1 = d2[1], p2 = d2[2], p3 = d2[3];
      x0 = p0.x; x1 = p0.y; x2 = p1.x; x3 = p1.y;
      x4 = p2.x; x5 = p2.y; x6 = p3.x; x7 = p3.y;
    } else {
      // lazy fold: kept rows of group g-1 into rem[w], w > g
      int w = t - 64;
      int gp = g - 1;
      if (gp >= 0 && w > g && w < ng) {
        int nkp = nk_sh[gp & 1];
        if (nkp) {
          const int* kp = kept[gp & 1];
          int basep = gp << 6;
          u64 acc = 0;
          for (int i = 0; i < nkp; i += 16) {
            int k0 = kp[i+0],  k1 = kp[i+1],  k2 = kp[i+2],  k3 = kp[i+3];
            int k4 = kp[i+4],  k5 = kp[i+5],  k6 = kp[i+6],  k7 = kp[i+7];
            int k8 = kp[i+8],  k9 = kp[i+9],  k10 = kp[i+10], k11 = kp[i+11];
            int k12 = kp[i+12], k13 = kp[i+13], k14 = kp[i+14], k15 = kp[i+15];
            u64 v0 = mask[(size_t)(basep + k0) * wstride + w];
            u64 v1 = mask[(size_t)(basep + k1) * wstride + w];
            u64 v2 = mask[(size_t)(basep + k2) * wstride + w];
            u64 v3 = mask[(size_t)(basep + k3) * wstride + w];
            u64 v4 = mask[(size_t)(basep + k4) * wstride + w];
            u64 v5 = mask[(size_t)(basep + k5) * wstride + w];
            u64 v6 = mask[(size_t)(basep + k6) * wstride + w];
            u64 v7 = mask[(size_t)(basep + k7) * wstride + w];
            u64 v8 = mask[(size_t)(basep + k8) * wstride + w];
            u64 v9 = mask[(size_t)(basep + k9) * wstride + w];
            u64 v10 = mask[(size_t)(basep + k10) * wstride + w];
            u64 v11 = mask[(size_t)(basep + k11) * wstride + w];
            u64 v12 = mask[(size_t)(basep + k12) * wstride + w];
            u64 v13 = mask[(size_t)(basep + k13) * wstride + w];
            u64 v14 = mask[(size_t)(basep + k14) * wstride + w];
            u64 v15 = mask[(size_t)(basep + k15) * wstride + w];
            acc |= v0;
            if (i + 1 < nkp)  acc |= v1;
            if (i + 2 < nkp)  acc |= v2;
            if (i + 3 < nkp)  acc |= v3;
            if (i + 4 < nkp)  acc |= v4;
            if (i + 5 < nkp)  acc |= v5;
            if (i + 6 < nkp)  acc |= v6;
            if (i + 7 < nkp)  acc |= v7;
            if (i + 8 < nkp)  acc |= v8;
            if (i + 9 < nkp)  acc |= v9;
            if (i + 10 < nkp) acc |= v10;
            if (i + 11 < nkp) acc |= v11;
            if (i + 12 < nkp) acc |= v12;
            if (i + 13 < nkp) acc |= v13;
            if (i + 14 < nkp) acc |= v14;
            if (i + 15 < nkp) acc |= v15;
          }
          rem[w] |= acc;
        }
      }
    }
    __syncthreads();
  }
  // final scatter: sorted keep bits -> original order (parallel, coalesced sidx)
  for (int k = t; k < n; k += 256) {
    u64 kwv = kwords[k >> 6];
    keep[sidx[k]] = ((kwv >> (k & 63)) & 1ull) ? 1.0f : 0.0f;
  }
}

__global__ __launch_bounds__(256, 1) void k_scan2(const u64* __restrict__ mask,
                                                  const u64* __restrict__ diag,
                                                  const u64* __restrict__ band,
                                                  const int* __restrict__ sidx,
                                                  float* __restrict__ keep,
                                                  int n, int wstride) {
  __shared__ u64 rem[256];
  __shared__ __align__(16) u64 dsh[64];
  __shared__ u64 bsh[64];
  __shared__ u64 kwords[160];
  __shared__ int kept[2][64];
  __shared__ int nk_sh[2];
  scan_body7(mask, diag, band, sidx, keep, n, wstride, rem, dsh, bsh, kwords, kept, nk_sh);
}

// Pairwise IoU, original order, WITH clamp. Loose 2e-2 threshold -> fast rcp.
__device__ __forceinline__ float iou_one(float li, float ti, float ri, float bi, float ai,
                                         float lj, float tj, float rj, float bj, float aj) {
  float lmax = fmaxf(li, lj);
  float tmax = fmaxf(ti, tj);
  float rmin = fminf(ri, rj);
  float bmin = fminf(bi, bj);
  float w = fmaxf(rmin - lmax, 0.0f);
  float h = fmaxf(bmin - tmax, 0.0f);
  float inter = w * h;
  float denom = (ai + aj) - inter;
  return inter * __builtin_amdgcn_rcpf(denom);
}

__device__ __forceinline__ void iou_body(const float4* __restrict__ boxes,
                                         float* __restrict__ out,
                                         int n, int rpb, int bx, int by) {
  int nj4 = (n + 3) >> 2;
  int j4 = bx * 256 + threadIdx.x;
  if (j4 >= nj4) return;
  int j = j4 << 2;
  int jc1 = min(j + 1, n - 1), jc2 = min(j + 2, n - 1), jc3 = min(j + 3, n - 1);
  float l0,t0,r0,b0,a0, l1,t1,r1,b1,a1, l2,t2,r2,b2,a2, l3,t3,r3,b3,a3;
  conv_box(boxes[j],   l0,t0,r0,b0,a0);
  conv_box(boxes[jc1], l1,t1,r1,b1,a1);
  conv_box(boxes[jc2], l2,t2,r2,b2,a2);
  conv_box(boxes[jc3], l3,t3,r3,b3,a3);
  bool full = (j + 3) < n;
  for (int rr = 0; rr < rpb; ++rr) {
    int i = by * rpb + rr;
    if (i >= n) return;
    float li,ti,ri,bi,ai;
    conv_box(boxes[i], li,ti,ri,bi,ai);
    float4 o;
    o.x = iou_one(li,ti,ri,bi,ai, l0,t0,r0,b0,a0);
    o.y = iou_one(li,ti,ri,bi,ai, l1,t1,r1,b1,a1);
    o.z = iou_one(li,ti,ri,bi,ai, l2,t2,r2,b2,a2);
    o.w = iou_one(li,ti,ri,bi,ai, l3,t3,r3,b3,a3);
    size_t row = (size_t)i * n;
    if (full) {
      *reinterpret_cast<float4*>(out + row + j) = o;
    } else {
      out[row + j] = o.x;
      if (j + 1 < n) out[row + j + 1] = o.y;
      if (j + 2 < n) out[row + j + 2] = o.z;
    }
  }
}

__global__ void k_iou(const float4* __restrict__ boxes, float* __restrict__ out,
                      int n, int rpb) {
  iou_body(boxes, out, n, rpb, blockIdx.x, blockIdx.y);
}

// Fused: block 0 runs the NMS scan from d_ws while all other blocks stream
// the 400MB IoU matrix — scan latency hides under the write-bound IoU.
// launch_bounds(256,4): cap VGPR at 128 so the scan chain stays in registers
// (round-5: cap 64VGPR -> per-chunk LDS waits dominated).
__global__ __launch_bounds__(256, 4) void k_fused(const float4* __restrict__ boxes,
                                                  float* __restrict__ out,
                                                  const u64* __restrict__ mask,
                                                  const u64* __restrict__ diag,
                                                  const u64* __restrict__ band,
                                                  const int* __restrict__ sidx,
                                                  float* __restrict__ keep,
                                                  int n, int wstride, int rpb, int gx) {
  __shared__ u64 rem[256];
  __shared__ __align__(16) u64 dsh[64];
  __shared__ u64 bsh[64];
  __shared__ u64 kwords[160];
  __shared__ int kept[2][64];
  __shared__ int nk_sh[2];
  if (blockIdx.x == 0) {
    scan_body7(mask, diag, band, sidx, keep, n, wstride, rem, dsh, bsh, kwords, kept, nk_sh);
    return;
  }
  int id = blockIdx.x - 1;
  iou_body(boxes, out, n, rpb, id % gx, id / gx);
}

extern "C" void kernel_launch(void* const* d_in, const int* in_sizes, int n_in,
                              void* d_out, int out_size, void* d_ws, size_t ws_size,
                              hipStream_t stream) {
  const float* boxes = (const float*)d_in[0];
  const float* scores = (const float*)d_in[1];
  int n = in_sizes[1];
  float* out = (float*)d_out;
  size_t NN = (size_t)n * (size_t)n;
  float* keep = out + NN;

  int words = (n + 63) >> 6;
  int wstride = (words + 3) & ~3;
  size_t need = (size_t)n * wstride * 8          // mask
              + (size_t)words * 64 * 8 * 2       // diag + band
              + 256                              // align slack
              + (size_t)n * 4 * 6;               // sl,st,sr,sb,sa,sidx
  bool use_ws = (ws_size >= need);

  char* base = use_ws ? (char*)d_ws : (char*)d_out;
  size_t off = 0;
  u64* mask = (u64*)(base + off); off += (size_t)n * wstride * 8;
  u64* diag = (u64*)(base + off); off += (size_t)words * 64 * 8;
  u64* band = (u64*)(base + off); off += (size_t)words * 64 * 8;
  off = (off + 255) & ~(size_t)255;
  float* sl  = (float*)(base + off); off += (size_t)n * 4;
  float* st_ = (float*)(base + off); off += (size_t)n * 4;
  float* sr  = (float*)(base + off); off += (size_t)n * 4;
  float* sb  = (float*)(base + off); off += (size_t)n * 4;
  float* sa  = (float*)(base + off); off += (size_t)n * 4;
  int* sidx  = (int*)(base + off); off += (size_t)n * 4;

  int nb = (n + 255) / 256;
  k_rankscatter<<<nb, 256, 0, stream>>>((const float4*)boxes, scores,
                                        sl, st_, sr, sb, sa, sidx, n);

  k_mask<<<dim3(nb, words), 256, 0, stream>>>(sl, st_, sr, sb, sa, mask, diag, band, n, wstride);

  int rpb = 10;
  int nj4 = (n + 3) >> 2;
  int gx = (nj4 + 255) / 256;
  int gy = (n + rpb - 1) / rpb;

  if (use_ws) {
    k_fused<<<gx * gy + 1, 256, 0, stream>>>((const float4*)boxes, out, mask, diag,
                                             band, sidx, keep, n, wstride, rpb, gx);
  } else {
    // scratch lives in front of out: must finish scan before iou overwrites it
    k_scan2<<<1, 256, 0, stream>>>(mask, diag, band, sidx, keep, n, wstride);
    k_iou<<<dim3(gx, gy), 256, 0, stream>>>((const float4*)boxes, out, n, rpb);
  }
}

// Round 7
// 389.867 us; speedup vs baseline: 1.8396x; 1.8396x over previous
//
#include <hip/hip_runtime.h>

typedef unsigned long long u64;

#define THR 0.5f

// Convert one cxcywh box to ltrb + area, with FP contraction OFF so every op
// matches numpy's rn-per-op semantics bit-exactly (needed for the NMS >= 0.5
// predicate; a fused cx - 0.5*w -> fma differs in the last ulp).
__device__ __forceinline__ void conv_box(const float4 b, float& l, float& t,
                                         float& r, float& bo, float& a) {
  #pragma clang fp contract(off)
  float hw = 0.5f * b.z;
  float hh = 0.5f * b.w;
  l = b.x - hw;
  t = b.y - hh;
  r = b.x + hw;
  bo = b.y + hh;
  a = (r - l) * (bo - t);
}

__global__ void k_zero(int* __restrict__ rank, int n) {
  int i = blockIdx.x * blockDim.x + threadIdx.x;
  if (i < n) rank[i] = 0;
}

// Stable descending rank == stable argsort(-scores) position. j-chunked over
// blockIdx.y for parallelism (round-6 lesson: a single thread scanning all n
// scores = 40 blocks total = no latency hiding, 372us).
__global__ void k_rank(const float* __restrict__ scores, int* __restrict__ rank,
                       int n, int jchunk) {
  int i = blockIdx.x * blockDim.x + threadIdx.x;
  if (i >= n) return;
  float si = scores[i];
  int j0 = blockIdx.y * jchunk;
  int j1 = min(j0 + jchunk, n);
  int c = 0;
  for (int j = j0; j < j1; ++j) {
    float sj = scores[j];
    c += ((sj > si) || (sj == si && j < i)) ? 1 : 0;
  }
  if (c) atomicAdd(rank + i, c);
}

__global__ void k_scatter(const float4* __restrict__ boxes, const int* __restrict__ rank,
                          float* __restrict__ sl, float* __restrict__ st,
                          float* __restrict__ sr, float* __restrict__ sb,
                          float* __restrict__ sa, int* __restrict__ sidx, int n) {
  int i = blockIdx.x * blockDim.x + threadIdx.x;
  if (i >= n) return;
  float l, t, r, b, a;
  conv_box(boxes[i], l, t, r, b, a);
  int k = rank[i];
  sl[k] = l; st[k] = t; sr[k] = r; sb[k] = b; sa[k] = a; sidx[k] = i;
}

// mask[k][w] bit b (j = w*64+b) set iff j>k, j<n, iou_nms(k,j) >= 0.5.
// Also emits diag (diagonal 64x64 block) and band (superdiagonal word
// mask[k][(k>>6)+1]) for the scan. Reference does NOT clamp the intersection
// on the NMS path — replicate exactly (contraction off, IEEE f32 div).
__global__ void k_mask(const float* __restrict__ sl, const float* __restrict__ st,
                       const float* __restrict__ sr, const float* __restrict__ sb,
                       const float* __restrict__ sa,
                       u64* __restrict__ mask, u64* __restrict__ diag,
                       u64* __restrict__ band, int n, int wstride) {
  #pragma clang fp contract(off)
  int k = blockIdx.x * blockDim.x + threadIdx.x;
  if (k >= n) return;
  int w = blockIdx.y;
  int jbase = w << 6;
  u64 word = 0;
  if (jbase + 63 > k) {
    float l = sl[k], t = st[k], r = sr[k], b = sb[k], a = sa[k];
    int jend = min(jbase + 64, n);
    for (int j = max(jbase, k + 1); j < jend; ++j) {
      float lmax = fmaxf(l, sl[j]);
      float tmax = fmaxf(t, st[j]);
      float rmin = fminf(r, sr[j]);
      float bmin = fminf(b, sb[j]);
      float wd = rmin - lmax;
      float hd = bmin - tmax;
      float inter = wd * hd;               // no clamp (matches reference NMS path)
      float denom = (a + sa[j]) - inter;
      float q = inter / denom;             // IEEE f32 div
      if (q >= THR) word |= 1ull << (j - jbase);
    }
  }
  mask[(size_t)k * wstride + w] = word;
  int kg = k >> 6;
  if (kg == w) diag[k] = word;
  if (w == kg + 1) band[k] = word;
}

// Canonical GCN wave64 OR-reduce: DPP row_shr 1/2/4/8 + bcast15/31 (VALU
// latency ~4-8cy/step) instead of 6 dependent u64 shfl_xor (~120cy bpermutes).
__device__ __forceinline__ u64 wave_or_u64(u64 v) {
  unsigned lo = (unsigned)v, hi = (unsigned)(v >> 32);
#define DPP_OR(x, ctrl, rmask) \
  x |= (unsigned)__builtin_amdgcn_update_dpp(0, (int)(x), ctrl, rmask, 0xF, true)
  DPP_OR(lo, 0x111, 0xF); DPP_OR(hi, 0x111, 0xF);   // row_shr:1
  DPP_OR(lo, 0x112, 0xF); DPP_OR(hi, 0x112, 0xF);   // row_shr:2
  DPP_OR(lo, 0x114, 0xF); DPP_OR(hi, 0x114, 0xF);   // row_shr:4
  DPP_OR(lo, 0x118, 0xF); DPP_OR(hi, 0x118, 0xF);   // row_shr:8
  DPP_OR(lo, 0x142, 0xA); DPP_OR(hi, 0x142, 0xA);   // row_bcast:15 rows 1,3
  DPP_OR(lo, 0x143, 0xC); DPP_OR(hi, 0x143, 0xC);   // row_bcast:31 rows 2,3
#undef DPP_OR
  unsigned flo = (unsigned)__builtin_amdgcn_readlane((int)lo, 63);
  unsigned fhi = (unsigned)__builtin_amdgcn_readlane((int)hi, 63);
  return ((u64)fhi << 32) | flo;
}

// ---------------------------------------------------------------------------
// Greedy serial NMS scan — 256 threads.
//  wave 0: serial chain with the diag block REGISTER-double-buffered
//    (ulonglong2 LDS loads; chunk c+1 issued before compute c; chunk 0 of the
//    next group pre-read BEFORE the barrier).
//  band word for g+1 via DPP wave-OR (register, no global/LDS latency).
//  keep bits parked in LDS kwords[]; scattered once after the loop.
//  waves 1-3: lazy fold of group g-1's kept rows into rem[w], w>g, concurrent
//    with the chain; 16-deep independent coalesced loads.
// ---------------------------------------------------------------------------
__device__ __forceinline__ void scan_body7(
    const u64* __restrict__ mask, const u64* __restrict__ diag,
    const u64* __restrict__ band, const int* __restrict__ sidx,
    float* __restrict__ keep, int n, int wstride,
    u64* rem, u64* dsh, u64* bsh, u64* kwords, int (*kept)[64], int* nk_sh) {
  int t = threadIdx.x, wv = t >> 6, lane = t & 63;
  int ng = (n + 63) >> 6;
  rem[t] = 0;
  if (t < 2) nk_sh[t] = 0;
  u64 bnd = 0;
  u64 x0 = 0, x1 = 0, x2 = 0, x3 = 0, x4 = 0, x5 = 0, x6 = 0, x7 = 0;
  const ulonglong2* d2 = (const ulonglong2*)dsh;
  if (wv == 0) {
    dsh[lane] = diag[lane];
    bsh[lane] = band[lane];
    ulonglong2 p0 = d2[0], p1 = d2[1], p2 = d2[2], p3 = d2[3];
    x0 = p0.x; x1 = p0.y; x2 = p1.x; x3 = p1.y;
    x4 = p2.x; x5 = p2.y; x6 = p3.x; x7 = p3.y;
  }
  __syncthreads();
  for (int g = 0; g < ng; ++g) {
    int base = g << 6;
    if (wv == 0) {
      // prefetch next group's diag/band (global; hides under the chain)
      int nxt = base + 64 + lane;
      u64 dnext = (g + 1 < ng) ? diag[nxt] : 0;
      u64 bnext = (g + 1 < ng) ? band[nxt] : 0;
      u64 bshv = bsh[lane];                 // parallel LDS read, off-chain
      u64 s = rem[g] | bnd;                 // bnd = group g-1's word-g bits
      int valid = n - base;
      if (valid < 64) s |= (~0ull) << valid;  // nonexistent boxes = suppressed
      u64 kw = 0;
      u64 y0, y1, y2, y3, y4, y5, y6, y7;
#define LDC(a0,a1,a2,a3,a4,a5,a6,a7, c) { \
      ulonglong2 q0 = d2[4*(c)], q1 = d2[4*(c)+1], q2 = d2[4*(c)+2], q3 = d2[4*(c)+3]; \
      a0 = q0.x; a1 = q0.y; a2 = q1.x; a3 = q1.y; a4 = q2.x; a5 = q2.y; a6 = q3.x; a7 = q3.y; }
#define STEP(BB, EQ) if (!((s >> (BB)) & 1ull)) { kw |= 1ull << (BB); s |= EQ; }
#define CHUNK(b0v, a0,a1,a2,a3,a4,a5,a6,a7) \
      if ((unsigned)((s >> (b0v)) & 0xFFull) != 0xFFu) { \
        STEP(b0v+0, a0) STEP(b0v+1, a1) STEP(b0v+2, a2) STEP(b0v+3, a3) \
        STEP(b0v+4, a4) STEP(b0v+5, a5) STEP(b0v+6, a6) STEP(b0v+7, a7) }
      LDC(y0,y1,y2,y3,y4,y5,y6,y7, 1); CHUNK(0,  x0,x1,x2,x3,x4,x5,x6,x7);
      LDC(x0,x1,x2,x3,x4,x5,x6,x7, 2); CHUNK(8,  y0,y1,y2,y3,y4,y5,y6,y7);
      LDC(y0,y1,y2,y3,y4,y5,y6,y7, 3); CHUNK(16, x0,x1,x2,x3,x4,x5,x6,x7);
      LDC(x0,x1,x2,x3,x4,x5,x6,x7, 4); CHUNK(24, y0,y1,y2,y3,y4,y5,y6,y7);
      LDC(y0,y1,y2,y3,y4,y5,y6,y7, 5); CHUNK(32, x0,x1,x2,x3,x4,x5,x6,x7);
      LDC(x0,x1,x2,x3,x4,x5,x6,x7, 6); CHUNK(40, y0,y1,y2,y3,y4,y5,y6,y7);
      LDC(y0,y1,y2,y3,y4,y5,y6,y7, 7); CHUNK(48, x0,x1,x2,x3,x4,x5,x6,x7);
                                       CHUNK(56, y0,y1,y2,y3,y4,y5,y6,y7);
#undef CHUNK
#undef STEP
#undef LDC
      if (lane == 0) kwords[g] = kw;
      // compact kept bits -> double-buffered LDS list, pad to x16 with 0
      int nk = __popcll(kw);
      if ((kw >> lane) & 1ull) {
        int pos = __popcll(kw & ((1ull << lane) - 1ull));
        kept[g & 1][pos] = lane;
      }
      int npad = (nk + 15) & ~15;
      if (lane >= nk && lane < npad) kept[g & 1][lane] = 0;
      if (lane == 0) nk_sh[g & 1] = nk;
      // band word for group g+1: DPP wave-OR of kept lanes' superdiag words
      u64 bv = ((kw >> lane) & 1ull) ? bshv : 0ull;
      bnd = wave_or_u64(bv);
      dsh[lane] = dnext;     // after all chain reads (wave-ordered LDS)
      bsh[lane] = bnext;
      // pre-read chunk 0 of the NEXT group before the barrier
      ulonglong2 p0 = d2[0], p1 = d2[1], p2 = d2[2], p3 = d2[3];
      x0 = p0.x; x1 = p0.y; x2 = p1.x; x3 = p1.y;
      x4 = p2.x; x5 = p2.y; x6 = p3.x; x7 = p3.y;
    } else {
      // lazy fold: kept rows of group g-1 into rem[w], w > g
      int w = t - 64;
      int gp = g - 1;
      if (gp >= 0 && w > g && w < ng) {
        int nkp = nk_sh[gp & 1];
        if (nkp) {
          const int* kp = kept[gp & 1];
          int basep = gp << 6;
          u64 acc = 0;
          for (int i = 0; i < nkp; i += 16) {
            int k0 = kp[i+0],  k1 = kp[i+1],  k2 = kp[i+2],  k3 = kp[i+3];
            int k4 = kp[i+4],  k5 = kp[i+5],  k6 = kp[i+6],  k7 = kp[i+7];
            int k8 = kp[i+8],  k9 = kp[i+9],  k10 = kp[i+10], k11 = kp[i+11];
            int k12 = kp[i+12], k13 = kp[i+13], k14 = kp[i+14], k15 = kp[i+15];
            u64 v0 = mask[(size_t)(basep + k0) * wstride + w];
            u64 v1 = mask[(size_t)(basep + k1) * wstride + w];
            u64 v2 = mask[(size_t)(basep + k2) * wstride + w];
            u64 v3 = mask[(size_t)(basep + k3) * wstride + w];
            u64 v4 = mask[(size_t)(basep + k4) * wstride + w];
            u64 v5 = mask[(size_t)(basep + k5) * wstride + w];
            u64 v6 = mask[(size_t)(basep + k6) * wstride + w];
            u64 v7 = mask[(size_t)(basep + k7) * wstride + w];
            u64 v8 = mask[(size_t)(basep + k8) * wstride + w];
            u64 v9 = mask[(size_t)(basep + k9) * wstride + w];
            u64 v10 = mask[(size_t)(basep + k10) * wstride + w];
            u64 v11 = mask[(size_t)(basep + k11) * wstride + w];
            u64 v12 = mask[(size_t)(basep + k12) * wstride + w];
            u64 v13 = mask[(size_t)(basep + k13) * wstride + w];
            u64 v14 = mask[(size_t)(basep + k14) * wstride + w];
            u64 v15 = mask[(size_t)(basep + k15) * wstride + w];
            acc |= v0;
            if (i + 1 < nkp)  acc |= v1;
            if (i + 2 < nkp)  acc |= v2;
            if (i + 3 < nkp)  acc |= v3;
            if (i + 4 < nkp)  acc |= v4;
            if (i + 5 < nkp)  acc |= v5;
            if (i + 6 < nkp)  acc |= v6;
            if (i + 7 < nkp)  acc |= v7;
            if (i + 8 < nkp)  acc |= v8;
            if (i + 9 < nkp)  acc |= v9;
            if (i + 10 < nkp) acc |= v10;
            if (i + 11 < nkp) acc |= v11;
            if (i + 12 < nkp) acc |= v12;
            if (i + 13 < nkp) acc |= v13;
            if (i + 14 < nkp) acc |= v14;
            if (i + 15 < nkp) acc |= v15;
          }
          rem[w] |= acc;
        }
      }
    }
    __syncthreads();
  }
  // final scatter: sorted keep bits -> original order (parallel, coalesced sidx)
  for (int k = t; k < n; k += 256) {
    u64 kwv = kwords[k >> 6];
    keep[sidx[k]] = ((kwv >> (k & 63)) & 1ull) ? 1.0f : 0.0f;
  }
}

__global__ __launch_bounds__(256, 1) void k_scan2(const u64* __restrict__ mask,
                                                  const u64* __restrict__ diag,
                                                  const u64* __restrict__ band,
                                                  const int* __restrict__ sidx,
                                                  float* __restrict__ keep,
                                                  int n, int wstride) {
  __shared__ u64 rem[256];
  __shared__ __align__(16) u64 dsh[64];
  __shared__ u64 bsh[64];
  __shared__ u64 kwords[160];
  __shared__ int kept[2][64];
  __shared__ int nk_sh[2];
  scan_body7(mask, diag, band, sidx, keep, n, wstride, rem, dsh, bsh, kwords, kept, nk_sh);
}

// Pairwise IoU, original order, WITH clamp. Loose 2e-2 threshold -> fast rcp.
__device__ __forceinline__ float iou_one(float li, float ti, float ri, float bi, float ai,
                                         float lj, float tj, float rj, float bj, float aj) {
  float lmax = fmaxf(li, lj);
  float tmax = fmaxf(ti, tj);
  float rmin = fminf(ri, rj);
  float bmin = fminf(bi, bj);
  float w = fmaxf(rmin - lmax, 0.0f);
  float h = fmaxf(bmin - tmax, 0.0f);
  float inter = w * h;
  float denom = (ai + aj) - inter;
  return inter * __builtin_amdgcn_rcpf(denom);
}

__device__ __forceinline__ void iou_body(const float4* __restrict__ boxes,
                                         float* __restrict__ out,
                                         int n, int rpb, int bx, int by) {
  int nj4 = (n + 3) >> 2;
  int j4 = bx * 256 + threadIdx.x;
  if (j4 >= nj4) return;
  int j = j4 << 2;
  int jc1 = min(j + 1, n - 1), jc2 = min(j + 2, n - 1), jc3 = min(j + 3, n - 1);
  float l0,t0,r0,b0,a0, l1,t1,r1,b1,a1, l2,t2,r2,b2,a2, l3,t3,r3,b3,a3;
  conv_box(boxes[j],   l0,t0,r0,b0,a0);
  conv_box(boxes[jc1], l1,t1,r1,b1,a1);
  conv_box(boxes[jc2], l2,t2,r2,b2,a2);
  conv_box(boxes[jc3], l3,t3,r3,b3,a3);
  bool full = (j + 3) < n;
  for (int rr = 0; rr < rpb; ++rr) {
    int i = by * rpb + rr;
    if (i >= n) return;
    float li,ti,ri,bi,ai;
    conv_box(boxes[i], li,ti,ri,bi,ai);
    float4 o;
    o.x = iou_one(li,ti,ri,bi,ai, l0,t0,r0,b0,a0);
    o.y = iou_one(li,ti,ri,bi,ai, l1,t1,r1,b1,a1);
    o.z = iou_one(li,ti,ri,bi,ai, l2,t2,r2,b2,a2);
    o.w = iou_one(li,ti,ri,bi,ai, l3,t3,r3,b3,a3);
    size_t row = (size_t)i * n;
    if (full) {
      *reinterpret_cast<float4*>(out + row + j) = o;
    } else {
      out[row + j] = o.x;
      if (j + 1 < n) out[row + j + 1] = o.y;
      if (j + 2 < n) out[row + j + 2] = o.z;
    }
  }
}

__global__ void k_iou(const float4* __restrict__ boxes, float* __restrict__ out,
                      int n, int rpb) {
  iou_body(boxes, out, n, rpb, blockIdx.x, blockIdx.y);
}

// Fused: block 0 runs the NMS scan from d_ws while all other blocks stream
// the 400MB IoU matrix — scan latency hides under the write-bound IoU.
// launch_bounds(256,4): cap VGPR at 128 so the scan chain stays in registers.
__global__ __launch_bounds__(256, 4) void k_fused(const float4* __restrict__ boxes,
                                                  float* __restrict__ out,
                                                  const u64* __restrict__ mask,
                                                  const u64* __restrict__ diag,
                                                  const u64* __restrict__ band,
                                                  const int* __restrict__ sidx,
                                                  float* __restrict__ keep,
                                                  int n, int wstride, int rpb, int gx) {
  __shared__ u64 rem[256];
  __shared__ __align__(16) u64 dsh[64];
  __shared__ u64 bsh[64];
  __shared__ u64 kwords[160];
  __shared__ int kept[2][64];
  __shared__ int nk_sh[2];
  if (blockIdx.x == 0) {
    scan_body7(mask, diag, band, sidx, keep, n, wstride, rem, dsh, bsh, kwords, kept, nk_sh);
    return;
  }
  int id = blockIdx.x - 1;
  iou_body(boxes, out, n, rpb, id % gx, id / gx);
}

extern "C" void kernel_launch(void* const* d_in, const int* in_sizes, int n_in,
                              void* d_out, int out_size, void* d_ws, size_t ws_size,
                              hipStream_t stream) {
  const float* boxes = (const float*)d_in[0];
  const float* scores = (const float*)d_in[1];
  int n = in_sizes[1];
  float* out = (float*)d_out;
  size_t NN = (size_t)n * (size_t)n;
  float* keep = out + NN;

  int words = (n + 63) >> 6;
  int wstride = (words + 3) & ~3;
  size_t need = (size_t)n * wstride * 8          // mask
              + (size_t)words * 64 * 8 * 2       // diag + band
              + 256                              // align slack
              + (size_t)n * 4 * 7;               // sl,st,sr,sb,sa,sidx,rank
  bool use_ws = (ws_size >= need);

  char* base = use_ws ? (char*)d_ws : (char*)d_out;
  size_t off = 0;
  u64* mask = (u64*)(base + off); off += (size_t)n * wstride * 8;
  u64* diag = (u64*)(base + off); off += (size_t)words * 64 * 8;
  u64* band = (u64*)(base + off); off += (size_t)words * 64 * 8;
  off = (off + 255) & ~(size_t)255;
  float* sl  = (float*)(base + off); off += (size_t)n * 4;
  float* st_ = (float*)(base + off); off += (size_t)n * 4;
  float* sr  = (float*)(base + off); off += (size_t)n * 4;
  float* sb  = (float*)(base + off); off += (size_t)n * 4;
  float* sa  = (float*)(base + off); off += (size_t)n * 4;
  int* sidx  = (int*)(base + off); off += (size_t)n * 4;
  int* rank  = (int*)(base + off); off += (size_t)n * 4;

  int nb = (n + 255) / 256;
  k_zero<<<nb, 256, 0, stream>>>(rank, n);

  int jblocks = 40;
  int jchunk = (n + jblocks - 1) / jblocks;
  k_rank<<<dim3(nb, jblocks), 256, 0, stream>>>(scores, rank, n, jchunk);

  k_scatter<<<nb, 256, 0, stream>>>((const float4*)boxes, rank, sl, st_, sr, sb, sa, sidx, n);

  k_mask<<<dim3(nb, words), 256, 0, stream>>>(sl, st_, sr, sb, sa, mask, diag, band, n, wstride);

  int rpb = 10;
  int nj4 = (n + 3) >> 2;
  int gx = (nj4 + 255) / 256;
  int gy = (n + rpb - 1) / rpb;

  if (use_ws) {
    k_fused<<<gx * gy + 1, 256, 0, stream>>>((const float4*)boxes, out, mask, diag,
                                             band, sidx, keep, n, wstride, rpb, gx);
  } else {
    // scratch lives in front of out: must finish scan before iou overwrites it
    k_scan2<<<1, 256, 0, stream>>>(mask, diag, band, sidx, keep, n, wstride);
    k_iou<<<dim3(gx, gy), 256, 0, stream>>>((const float4*)boxes, out, n, rpb);
  }
}